// Round 6
// baseline (36.199 us; speedup 1.0000x reference)
//
#include <hip/hip_runtime.h>
#include <math.h>

#define D 64
#define DH 32

typedef __attribute__((ext_vector_type(8))) short bf16x8;   // MFMA A/B frag (4 VGPRs)
typedef __attribute__((ext_vector_type(4))) float f32x4;    // MFMA C/D frag

// fp32 -> bf16 RNE
static __device__ __forceinline__ unsigned short f2b(float f) {
    unsigned int u = __builtin_bit_cast(unsigned int, f);
    u += 0x7FFFu + ((u >> 16) & 1u);
    return (unsigned short)(u >> 16);
}
static __device__ __forceinline__ unsigned int pack_b2(float a, float b) {
    return (unsigned int)f2b(a) | ((unsigned int)f2b(b) << 16);
}
static __device__ __forceinline__ float gelu_exact(float v) {
    return 0.5f * v * (1.0f + erff(v * 0.70710678118654752f));
}

// ---------------------------------------------------------------------------
// Softmax over each row-segment sums to exactly 1, so
//   out[i] = has_edge(i) ? h[i]*(1+peak[i]) + bias : bias
// ---------------------------------------------------------------------------
__global__ void edge_flag_kernel(const int* __restrict__ row,
                                 unsigned char* __restrict__ flag, int E) {
    int i4 = (blockIdx.x * blockDim.x + threadIdx.x) * 4;
    if (i4 + 3 < E) {
        int4 r = *(const int4*)(row + i4);
        flag[r.x] = 1; flag[r.y] = 1; flag[r.z] = 1; flag[r.w] = 1;
    } else if (i4 < E) {
        for (int j = i4; j < E; ++j) flag[row[j]] = 1;
    }
}

// ---------------------------------------------------------------------------
// Prep: grid-stride zero of byte-flags + (block 0) pack per-lane MFMA frags.
// ---------------------------------------------------------------------------
__global__ void prep_kernel(const float* __restrict__ Wlin, const float* __restrict__ W1,
                            const float* __restrict__ bias, const float* __restrict__ b1,
                            const float* __restrict__ W2,
                            uint4* __restrict__ flag4, int nflag4,
                            unsigned short* __restrict__ packAW,
                            unsigned short* __restrict__ packAW1, float* __restrict__ packBias,
                            float* __restrict__ packB1, float* __restrict__ packW2)
{
    const int idx = blockIdx.x * blockDim.x + threadIdx.x;
    const int stride = gridDim.x * blockDim.x;
    const uint4 z = {0u, 0u, 0u, 0u};
    for (int i = idx; i < nflag4; i += stride) flag4[i] = z;

    if (blockIdx.x == 0) {
        const int lane = threadIdx.x & 63, part = threadIdx.x >> 6;  // 4 parts
        const int q = lane >> 4, m = lane & 15;
#pragma unroll
        for (int fo = 0; fo < 2; ++fo) {                 // packAW: frags 2*part, 2*part+1
            const int f = part * 2 + fo, nt = f >> 1, ks = f & 1;
#pragma unroll
            for (int j = 0; j < 8; ++j) {
                const int k = 32 * ks + 8 * q + j, n = 16 * nt + m;
                packAW[(f * 64 + lane) * 8 + j] = f2b(Wlin[k * D + n]);
            }
        }
        {                                                 // packAW1: frag = part
            const int f = part, ntW = f >> 1, ks = f & 1;
#pragma unroll
            for (int j = 0; j < 8; ++j) {
                const int k = 32 * ks + 8 * q + j, n = 16 * ntW + m;
                packAW1[(f * 64 + lane) * 8 + j] = f2b(W1[k * DH + n]);
            }
        }
#pragma unroll
        for (int r = 0; r < 4; ++r)                       // packBias: nt = part
            packBias[(part * 64 + lane) * 4 + r] = bias[16 * part + 4 * q + r];
        if (part < 2) {
#pragma unroll
            for (int r = 0; r < 4; ++r)
                packB1[(part * 64 + lane) * 4 + r] = b1[16 * part + 4 * q + r];
        } else {
#pragma unroll
            for (int r = 0; r < 4; ++r)
                packW2[((part - 2) * 64 + lane) * 4 + r] = W2[16 * (part - 2) + 4 * q + r];
        }
    }
}

// ---------------------------------------------------------------------------
// Main: 128 threads = 2 waves, 64 nodes/wave (4 M-tiles) for 4-way chain ILP.
// All independent global loads issued before compute; no barriers.
// ---------------------------------------------------------------------------
__global__ __launch_bounds__(128) void gat_mfma3(
    const float* __restrict__ x, const unsigned char* __restrict__ flag,
    const unsigned short* __restrict__ packAW, const unsigned short* __restrict__ packAW1,
    const float* __restrict__ packBias, const float* __restrict__ packB1,
    const float* __restrict__ packW2, const float* __restrict__ b2,
    float* __restrict__ out, int N)
{
    __shared__ unsigned short sH[2][64][72];   // per-wave h bf16 [node_loc][hcol], 18 KB

    const int tid  = threadIdx.x;
    const int wv   = tid >> 6;
    const int lane = tid & 63;
    const int q    = lane >> 4;
    const int m    = lane & 15;
    const int nodeBase = blockIdx.x * 128 + wv * 64;

    // ---- early independent loads: flags, x rows, b2 ----
    int gn[4]; unsigned char fl[4];
#pragma unroll
    for (int mt = 0; mt < 4; ++mt) {
        int g = nodeBase + 16 * mt + m;
        if (g > N - 1) g = N - 1;
        gn[mt] = g;
        fl[mt] = flag[g];
    }
    const float b2s = b2[0];

    float4 u[4][4];   // [mt][2*ks+half]
#pragma unroll
    for (int mt = 0; mt < 4; ++mt) {
        const float* px = x + (size_t)gn[mt] * D + 8 * q;
#pragma unroll
        for (int ks = 0; ks < 2; ++ks) {
            u[mt][2 * ks + 0] = *(const float4*)(px + 32 * ks);
            u[mt][2 * ks + 1] = *(const float4*)(px + 32 * ks + 4);
        }
    }

    // ---- W^T A-frags from pre-packed global (L2-hot, coalesced) ----
    bf16x8 aw[4][2];
#pragma unroll
    for (int nt = 0; nt < 4; ++nt)
#pragma unroll
        for (int ks = 0; ks < 2; ++ks)
            aw[nt][ks] = ((const bf16x8*)packAW)[(nt * 2 + ks) * 64 + lane];

    // ---- cvt x to bf16 B-frags ----
    bf16x8 bx[4][2];
#pragma unroll
    for (int mt = 0; mt < 4; ++mt)
#pragma unroll
        for (int ks = 0; ks < 2; ++ks) {
            const float4 u0 = u[mt][2 * ks + 0], u1 = u[mt][2 * ks + 1];
            uint4 pk;
            pk.x = pack_b2(u0.x, u0.y); pk.y = pack_b2(u0.z, u0.w);
            pk.z = pack_b2(u1.x, u1.y); pk.w = pack_b2(u1.z, u1.w);
            bx[mt][ks] = __builtin_bit_cast(bf16x8, pk);
        }

    // ---- GEMM1: h^T = W^T @ x^T (4 independent mt chains) ----
    f32x4 accH[4][4];
#pragma unroll
    for (int mt = 0; mt < 4; ++mt)
#pragma unroll
        for (int nt = 0; nt < 4; ++nt)
            accH[mt][nt] = (f32x4){0.f, 0.f, 0.f, 0.f};
#pragma unroll
    for (int ks = 0; ks < 2; ++ks)
#pragma unroll
        for (int mt = 0; mt < 4; ++mt)
#pragma unroll
            for (int nt = 0; nt < 4; ++nt)
                accH[mt][nt] = __builtin_amdgcn_mfma_f32_16x16x32_bf16(
                    aw[nt][ks], bx[mt][ks], accH[mt][nt], 0, 0, 0);
    // lane holds h[node=nodeBase+16mt+m][hcol=16nt+4q+r]

    // ---- h -> per-wave LDS (bf16 b64 writes), b128 frag reads (no barrier) ----
#pragma unroll
    for (int mt = 0; mt < 4; ++mt)
#pragma unroll
        for (int nt = 0; nt < 4; ++nt) {
            uint2 pk;
            pk.x = pack_b2(accH[mt][nt][0], accH[mt][nt][1]);
            pk.y = pack_b2(accH[mt][nt][2], accH[mt][nt][3]);
            *(uint2*)&sH[wv][16 * mt + m][16 * nt + 4 * q] = pk;
        }
    bf16x8 a2[4][2];
#pragma unroll
    for (int mt = 0; mt < 4; ++mt)
#pragma unroll
        for (int ks = 0; ks < 2; ++ks)
            a2[mt][ks] = *(const bf16x8*)&sH[wv][16 * mt + m][32 * ks + 8 * q];

    // ---- GEMM2: t^T = W1^T @ h^T ----
    bf16x8 aw1[2][2];
#pragma unroll
    for (int nt = 0; nt < 2; ++nt)
#pragma unroll
        for (int ks = 0; ks < 2; ++ks)
            aw1[nt][ks] = ((const bf16x8*)packAW1)[(nt * 2 + ks) * 64 + lane];
    const f32x4 b1v0 = ((const f32x4*)packB1)[0 * 64 + lane];
    const f32x4 b1v1 = ((const f32x4*)packB1)[1 * 64 + lane];
    f32x4 acc2[2][4];   // [ntW][mt]
#pragma unroll
    for (int mt = 0; mt < 4; ++mt) { acc2[0][mt] = b1v0; acc2[1][mt] = b1v1; }
#pragma unroll
    for (int ks = 0; ks < 2; ++ks)
#pragma unroll
        for (int nt = 0; nt < 2; ++nt)
#pragma unroll
            for (int mt = 0; mt < 4; ++mt)
                acc2[nt][mt] = __builtin_amdgcn_mfma_f32_16x16x32_bf16(
                    aw1[nt][ks], a2[mt][ks], acc2[nt][mt], 0, 0, 0);
    // lane holds t[node=nodeBase+16mt+m][w1col=16ntW+4q+r]

    // ---- peak: pp = sum gelu(t)*W2, reduce over the 4 q-groups ----
    const f32x4 w2v0 = ((const f32x4*)packW2)[0 * 64 + lane];
    const f32x4 w2v1 = ((const f32x4*)packW2)[1 * 64 + lane];
    float scale[4];
#pragma unroll
    for (int mt = 0; mt < 4; ++mt) {
        float pp = 0.f;
#pragma unroll
        for (int r = 0; r < 4; ++r) {
            pp = fmaf(gelu_exact(acc2[0][mt][r]), w2v0[r], pp);
            pp = fmaf(gelu_exact(acc2[1][mt][r]), w2v1[r], pp);
        }
        pp += __shfl_xor(pp, 16);
        pp += __shfl_xor(pp, 32);
        scale[mt] = (fl[mt] != 0) ? (1.f + 1.f / (1.f + expf(-(pp + b2s)))) : 0.f;
    }

    // ---- epilogue: out[node][16nt+4q+r] = h*scale + bias ----
    f32x4 biasv[4];
#pragma unroll
    for (int nt = 0; nt < 4; ++nt) biasv[nt] = ((const f32x4*)packBias)[nt * 64 + lane];
#pragma unroll
    for (int mt = 0; mt < 4; ++mt) {
        const int g = nodeBase + 16 * mt + m;
        if (g < N) {
            float* po = out + (size_t)g * D + 4 * q;
#pragma unroll
            for (int nt = 0; nt < 4; ++nt) {
                f32x4 o;
#pragma unroll
                for (int r = 0; r < 4; ++r)
                    o[r] = fmaf(accH[mt][nt][r], scale[mt], biasv[nt][r]);
                *(f32x4*)(po + 16 * nt) = o;
            }
        }
    }
}

extern "C" void kernel_launch(void* const* d_in, const int* in_sizes, int n_in,
                              void* d_out, int out_size, void* d_ws, size_t ws_size,
                              hipStream_t stream) {
    const float* x    = (const float*)d_in[0];
    const int*   eidx = (const int*)d_in[1];   // [2, E]: first E entries = row
    const float* Wlin = (const float*)d_in[2];
    // d_in[3] att_src, d_in[4] att_dst cancel (segment softmax sums to 1)
    const float* bias = (const float*)d_in[5];
    const float* W1   = (const float*)d_in[6];
    const float* b1   = (const float*)d_in[7];
    const float* W2   = (const float*)d_in[8];
    const float* b2   = (const float*)d_in[9];
    float* out = (float*)d_out;

    const int N = in_sizes[0] / D;
    const int E = in_sizes[1] / 2;

    char* ws = (char*)d_ws;
    unsigned char* flag = (unsigned char*)ws;
    const int nflag4 = (N + 15) / 16;                         // uint4 count for zeroing
    const size_t off = (((size_t)nflag4 * 16) + 255) & ~(size_t)255;
    unsigned short* packAW  = (unsigned short*)(ws + off);            // 8192 B
    unsigned short* packAW1 = (unsigned short*)(ws + off + 8192);     // 4096 B
    float*          packBias= (float*)(ws + off + 12288);             // 4096 B
    float*          packB1  = (float*)(ws + off + 16384);             // 2048 B
    float*          packW2  = (float*)(ws + off + 18432);             // 2048 B

    prep_kernel<<<128, 256, 0, stream>>>(Wlin, W1, bias, b1, W2,
                                         (uint4*)flag, nflag4,
                                         packAW, packAW1, packBias, packB1, packW2);
    edge_flag_kernel<<<(E / 4 + 255) / 256, 256, 0, stream>>>(eidx, flag, E);
    gat_mfma3<<<(N + 127) / 128, 128, 0, stream>>>(x, flag, packAW, packAW1,
                                                   packBias, packB1, packW2, b2, out, N);
}